// Round 1
// baseline (1693.752 us; speedup 1.0000x reference)
//
#include <hip/hip_runtime.h>
#include <hip/hip_bf16.h>
#include <cstddef>

// Problem constants (match reference)
#define N_IMG 65536
#define IMAGE_DIM 2048
#define N_CLS 2048
#define ATT_DIM 1024
#define ATT_HC 512
#define TEMP 10.0f
#define THRESH 0.17364817766693041f   // cos(80 deg), same for A and V

// ---------------- generic fp32 tiled GEMM ----------------
// C[M,N] = A[M,K] @ B  (B is [K,N] row-major if !BT, else [N,K] row-major -> A@B^T)
#define BM 64
#define BN 64
#define BKK 16

template <bool BT>
__global__ __launch_bounds__(256) void gemm_kernel(const float* __restrict__ A,
                                                   const float* __restrict__ B,
                                                   float* __restrict__ C,
                                                   int M, int N, int K) {
  __shared__ float As[BKK][BM + 1];
  __shared__ float Bs[BKK][BN + 1];
  const int t = threadIdx.x;
  const int bm = blockIdx.y * BM;
  const int bn = blockIdx.x * BN;
  const int tx = t & 15;        // 0..15
  const int ty = t >> 4;        // 0..15
  const int ar = t >> 2;        // 0..63 (row within tile for A / NT-B loads)
  const int ak = (t & 3) * 4;   // 0,4,8,12

  float acc[4][4] = {};

  for (int k0 = 0; k0 < K; k0 += BKK) {
    // A tile: 64 rows x 16 k, each thread one float4
    float4 av = *reinterpret_cast<const float4*>(&A[(size_t)(bm + ar) * K + k0 + ak]);
    As[ak + 0][ar] = av.x;
    As[ak + 1][ar] = av.y;
    As[ak + 2][ar] = av.z;
    As[ak + 3][ar] = av.w;
    if (BT) {
      // B is [N,K]; tile rows are output cols
      float4 bv = *reinterpret_cast<const float4*>(&B[(size_t)(bn + ar) * K + k0 + ak]);
      Bs[ak + 0][ar] = bv.x;
      Bs[ak + 1][ar] = bv.y;
      Bs[ak + 2][ar] = bv.z;
      Bs[ak + 3][ar] = bv.w;
    } else {
      const int bk = t >> 4;        // 0..15
      const int bn4 = (t & 15) * 4; // 0..60
      float4 bv = *reinterpret_cast<const float4*>(&B[(size_t)(k0 + bk) * N + bn + bn4]);
      Bs[bk][bn4 + 0] = bv.x;
      Bs[bk][bn4 + 1] = bv.y;
      Bs[bk][bn4 + 2] = bv.z;
      Bs[bk][bn4 + 3] = bv.w;
    }
    __syncthreads();

#pragma unroll
    for (int k = 0; k < BKK; ++k) {
      float a[4], b[4];
#pragma unroll
      for (int i = 0; i < 4; ++i) a[i] = As[k][ty * 4 + i];
#pragma unroll
      for (int j = 0; j < 4; ++j) b[j] = Bs[k][tx * 4 + j];
#pragma unroll
      for (int i = 0; i < 4; ++i)
#pragma unroll
        for (int j = 0; j < 4; ++j) acc[i][j] += a[i] * b[j];
    }
    __syncthreads();
  }

#pragma unroll
  for (int i = 0; i < 4; ++i) {
    float4 o;
    o.x = acc[i][0];
    o.y = acc[i][1];
    o.z = acc[i][2];
    o.w = acc[i][3];
    *reinterpret_cast<float4*>(&C[(size_t)(bm + ty * 4 + i) * N + bn + tx * 4]) = o;
  }
}

// ---------------- row L2-normalize in place ----------------
// x: [rows, D], D = 512, block = 128 threads (one float4 each)
__global__ __launch_bounds__(128) void rownorm_kernel(float* __restrict__ x, int D) {
  const int row = blockIdx.x;
  float* r = x + (size_t)row * D;
  const int t = threadIdx.x;
  float4 v = reinterpret_cast<float4*>(r)[t];
  float s = v.x * v.x + v.y * v.y + v.z * v.z + v.w * v.w;
#pragma unroll
  for (int off = 32; off > 0; off >>= 1) s += __shfl_down(s, off, 64);
  __shared__ float red[2];
  if ((t & 63) == 0) red[t >> 6] = s;
  __syncthreads();
  float tot = red[0] + red[1];
  float n = fmaxf(sqrtf(tot), 1e-8f);
  float inv = 1.0f / n;
  v.x *= inv; v.y *= inv; v.z *= inv; v.w *= inv;
  reinterpret_cast<float4*>(r)[t] = v;
}

// ---------------- masked softmax over rows of S [rows, N], N = 2048 ----------
// semantics: raw = where(S > thresh, S, -9e15); out = softmax(raw * T)
// non-passing entries underflow to exactly 0 in the reference -> write 0.
__global__ __launch_bounds__(256) void masked_softmax_kernel(float* __restrict__ S, int N) {
  const int row = blockIdx.x;
  float* r = S + (size_t)row * N;
  const int t = threadIdx.x;
  float4* rf = reinterpret_cast<float4*>(r);
  float4 v0 = rf[t];
  float4 v1 = rf[t + 256];
  float vals[8] = {v0.x, v0.y, v0.z, v0.w, v1.x, v1.y, v1.z, v1.w};

  __shared__ float red[4];

  // masked max of d
  float m = -1e30f;
#pragma unroll
  for (int i = 0; i < 8; ++i)
    if (vals[i] > THRESH) m = fmaxf(m, vals[i]);
#pragma unroll
  for (int off = 32; off > 0; off >>= 1) m = fmaxf(m, __shfl_xor(m, off));
  if ((t & 63) == 0) red[t >> 6] = m;
  __syncthreads();
  m = fmaxf(fmaxf(red[0], red[1]), fmaxf(red[2], red[3]));
  __syncthreads();

  // exp and sum
  float e[8];
  float s = 0.0f;
#pragma unroll
  for (int i = 0; i < 8; ++i) {
    e[i] = (vals[i] > THRESH) ? __expf((vals[i] - m) * TEMP) : 0.0f;
    s += e[i];
  }
#pragma unroll
  for (int off = 32; off > 0; off >>= 1) s += __shfl_xor(s, off);
  if ((t & 63) == 0) red[t >> 6] = s;
  __syncthreads();
  s = red[0] + red[1] + red[2] + red[3];
  float inv = 1.0f / s;

  v0.x = e[0] * inv; v0.y = e[1] * inv; v0.z = e[2] * inv; v0.w = e[3] * inv;
  v1.x = e[4] * inv; v1.y = e[5] * inv; v1.z = e[6] * inv; v1.w = e[7] * inv;
  rf[t] = v0;
  rf[t + 256] = v1;
}

// ---------------- segment mean machinery ----------------
__global__ void zero_ints_kernel(int* __restrict__ p, int n) {
  int i = blockIdx.x * 256 + threadIdx.x;
  if (i < n) p[i] = 0;
}

__global__ void count_kernel(const int* __restrict__ labels, int* __restrict__ counts, int n) {
  int i = blockIdx.x * 256 + threadIdx.x;
  if (i < n) atomicAdd(&counts[labels[i]], 1);
}

__global__ void scan_kernel(const int* __restrict__ counts, int* __restrict__ offs, int n) {
  if (threadIdx.x == 0 && blockIdx.x == 0) {
    int s = 0;
    for (int i = 0; i < n; ++i) {
      offs[i] = s;
      s += counts[i];
    }
  }
}

__global__ void scatter_kernel(const int* __restrict__ labels, const int* __restrict__ offs,
                               int* __restrict__ cursor, int* __restrict__ list, int n) {
  int i = blockIdx.x * 256 + threadIdx.x;
  if (i < n) {
    int l = labels[i];
    int pos = atomicAdd(&cursor[l], 1);
    list[offs[l] + pos] = i;
  }
}

// one block per output row j: mean of image rows of class target[j]
__global__ __launch_bounds__(512) void pool_kernel(const float* __restrict__ img,
                                                   const int* __restrict__ list,
                                                   const int* __restrict__ offs,
                                                   const int* __restrict__ counts,
                                                   const int* __restrict__ target,
                                                   float* __restrict__ protos) {
  const int j = blockIdx.x;
  const int c = target[j];
  const int beg = offs[c];
  const int cnt = counts[c];
  const int t = threadIdx.x; // 512 threads * float4 = 2048 dims
  float4 acc = {0.f, 0.f, 0.f, 0.f};
  for (int q = 0; q < cnt; ++q) {
    int idx = list[beg + q];
    float4 v = reinterpret_cast<const float4*>(img + (size_t)idx * IMAGE_DIM)[t];
    acc.x += v.x; acc.y += v.y; acc.z += v.z; acc.w += v.w;
  }
  float invc = 1.0f / (float)cnt;
  acc.x *= invc; acc.y *= invc; acc.z *= invc; acc.w *= invc;
  reinterpret_cast<float4*>(protos + (size_t)j * IMAGE_DIM)[t] = acc;
}

// ---------------- launch ----------------
extern "C" void kernel_launch(void* const* d_in, const int* in_sizes, int n_in,
                              void* d_out, int out_size, void* d_ws, size_t ws_size,
                              hipStream_t stream) {
  const float* image_feats = (const float*)d_in[0];   // [65536, 2048]
  const float* attributes = (const float*)d_in[1];    // [2048, 1024]
  const int* labels = (const int*)d_in[2];            // [65536]
  const int* target = (const int*)d_in[3];            // [2048]
  const float* att_g_a = (const float*)d_in[4];       // [1024, 512]
  const float* att_g_v = (const float*)d_in[5];       // [1024, 512]
  float* out = (float*)d_out;                         // [2048, 2048]

  char* w = (char*)d_ws;
  float* buf_a1 = (float*)w;                          // [2048, 512]   4 MiB (also a2)
  float* buf_attn = (float*)(w + (4u << 20));         // [2048, 2048] 16 MiB (attn1 then attention)
  float* buf_attout = (float*)(w + (20u << 20));      // [2048, 1024]  8 MiB
  float* buf_protos = (float*)(w + (28u << 20));      // [2048, 2048] 16 MiB
  int* counts = (int*)(w + (44u << 20));              // [2048]
  int* cursor = counts + N_CLS;                       // [2048]
  int* offs = cursor + N_CLS;                         // [2048]
  int* list = offs + N_CLS;                           // [65536]

  // ---- segment-mean index build ----
  zero_ints_kernel<<<(2 * N_CLS + 255) / 256, 256, 0, stream>>>(counts, 2 * N_CLS);
  count_kernel<<<(N_IMG + 255) / 256, 256, 0, stream>>>(labels, counts, N_IMG);
  scan_kernel<<<1, 64, 0, stream>>>(counts, offs, N_CLS);
  scatter_kernel<<<(N_IMG + 255) / 256, 256, 0, stream>>>(labels, offs, cursor, list, N_IMG);

  // ---- a1 = attributes @ att_g_a ----
  gemm_kernel<false><<<dim3(ATT_HC / BN, N_CLS / BM), 256, 0, stream>>>(
      attributes, att_g_a, buf_a1, N_CLS, ATT_HC, ATT_DIM);
  rownorm_kernel<<<N_CLS, 128, 0, stream>>>(buf_a1, ATT_HC);

  // ---- attn1 = softmax(mask(a1n @ a1n^T)) ----
  gemm_kernel<true><<<dim3(N_CLS / BN, N_CLS / BM), 256, 0, stream>>>(
      buf_a1, buf_a1, buf_attn, N_CLS, N_CLS, ATT_HC);
  masked_softmax_kernel<<<N_CLS, 256, 0, stream>>>(buf_attn, N_CLS);

  // ---- att_outs = attn1 @ attributes ----
  gemm_kernel<false><<<dim3(ATT_DIM / BN, N_CLS / BM), 256, 0, stream>>>(
      buf_attn, attributes, buf_attout, N_CLS, ATT_DIM, N_CLS);

  // ---- a2 = att_outs @ att_g_v ----
  gemm_kernel<false><<<dim3(ATT_HC / BN, N_CLS / BM), 256, 0, stream>>>(
      buf_attout, att_g_v, buf_a1, N_CLS, ATT_HC, ATT_DIM);
  rownorm_kernel<<<N_CLS, 128, 0, stream>>>(buf_a1, ATT_HC);

  // ---- attention = softmax(mask(a2n @ a2n^T)) ----
  gemm_kernel<true><<<dim3(N_CLS / BN, N_CLS / BM), 256, 0, stream>>>(
      buf_a1, buf_a1, buf_attn, N_CLS, N_CLS, ATT_HC);
  masked_softmax_kernel<<<N_CLS, 256, 0, stream>>>(buf_attn, N_CLS);

  // ---- protos (segment mean, reordered by target) ----
  pool_kernel<<<N_CLS, 512, 0, stream>>>(image_feats, list, offs, counts, target, buf_protos);

  // ---- out = attention @ protos ----
  gemm_kernel<false><<<dim3(IMAGE_DIM / BN, N_CLS / BM), 256, 0, stream>>>(
      buf_attn, buf_protos, out, N_CLS, IMAGE_DIM, N_CLS);
}

// Round 4
// 1014.029 us; speedup vs baseline: 1.6703x; 1.6703x over previous
//
#include <hip/hip_runtime.h>
#include <cstddef>
#include <cstdint>

#define N_IMG 65536
#define IMAGE_DIM 2048
#define N_CLS 2048
#define ATT_DIM 1024
#define ATT_HC 512
#define TEMP 10.0f
#define THRESH 0.17364817766693041f   // cos(80 deg)

typedef unsigned short u16;
typedef __bf16 bf16x8 __attribute__((ext_vector_type(8)));
typedef float f32x4 __attribute__((ext_vector_type(4)));
typedef unsigned short u16x4 __attribute__((ext_vector_type(4)));
typedef unsigned short u16x8 __attribute__((ext_vector_type(8)));

__device__ __forceinline__ u16 f2bf(float f) {
  unsigned u = __float_as_uint(f);
  u += 0x7fffu + ((u >> 16) & 1u);   // RNE
  return (u16)(u >> 16);
}

// ================= bf16 MFMA GEMM, NT form =================
// C[M,N] = A[M,K] @ B[N,K]^T ; A,B bf16 (as u16), C fp32 or bf16.
// 128x128 tile, BK=32, 256 threads = 4 waves (2x2), 4x4 16x16x32 frags/wave.
template <bool OUT_BF>
__global__ __launch_bounds__(256) void gemm_nt_bf16(const u16* __restrict__ A,
                                                    const u16* __restrict__ B,
                                                    void* __restrict__ Cv,
                                                    int M, int N, int K) {
  __shared__ alignas(16) u16 As[128][32];
  __shared__ alignas(16) u16 Bs[128][32];
  const int t = threadIdx.x;
  const int lane = t & 63;
  const int w = t >> 6;
  const int wm = (w >> 1) * 64;
  const int wn = (w & 1) * 64;
  const size_t bm = (size_t)blockIdx.y * 128;
  const size_t bn = (size_t)blockIdx.x * 128;

  f32x4 acc[4][4];
#pragma unroll
  for (int i = 0; i < 4; ++i)
#pragma unroll
    for (int j = 0; j < 4; ++j) acc[i][j] = (f32x4){0.f, 0.f, 0.f, 0.f};

  // staging: pass p covers rows p*64..p*64+63; thread t -> row p*64 + w*16 + lane/4,
  // k = (lane&3)*8 ; LDS byte = p*4096 + w*1024 + lane*16 (HW adds lane*16)
  const int srow = w * 16 + (lane >> 2);
  const int skol = (lane & 3) * 8;
  const u16* gA0 = A + (bm + srow) * (size_t)K + skol;
  const u16* gA1 = A + (bm + 64 + srow) * (size_t)K + skol;
  const u16* gB0 = B + (bn + srow) * (size_t)K + skol;
  const u16* gB1 = B + (bn + 64 + srow) * (size_t)K + skol;
  char* ldsA = (char*)&As[0][0] + w * 1024;
  char* ldsB = (char*)&Bs[0][0] + w * 1024;

  const int arow = wm + (lane & 15);
  const int brow = wn + (lane & 15);
  const int koff = (lane >> 4) * 8;

  for (int k0 = 0; k0 < K; k0 += 32) {
    __builtin_amdgcn_global_load_lds(
        (const __attribute__((address_space(1))) void*)(gA0 + k0),
        (__attribute__((address_space(3))) void*)(ldsA), 16, 0, 0);
    __builtin_amdgcn_global_load_lds(
        (const __attribute__((address_space(1))) void*)(gA1 + k0),
        (__attribute__((address_space(3))) void*)(ldsA + 4096), 16, 0, 0);
    __builtin_amdgcn_global_load_lds(
        (const __attribute__((address_space(1))) void*)(gB0 + k0),
        (__attribute__((address_space(3))) void*)(ldsB), 16, 0, 0);
    __builtin_amdgcn_global_load_lds(
        (const __attribute__((address_space(1))) void*)(gB1 + k0),
        (__attribute__((address_space(3))) void*)(ldsB + 4096), 16, 0, 0);
    __syncthreads();   // drains vmcnt: LDS tiles ready

    bf16x8 af[4], bfr[4];
#pragma unroll
    for (int m = 0; m < 4; ++m)
      af[m] = *reinterpret_cast<const bf16x8*>(&As[arow + m * 16][koff]);
#pragma unroll
    for (int n = 0; n < 4; ++n)
      bfr[n] = *reinterpret_cast<const bf16x8*>(&Bs[brow + n * 16][koff]);
#pragma unroll
    for (int m = 0; m < 4; ++m)
#pragma unroll
      for (int n = 0; n < 4; ++n)
        acc[m][n] = __builtin_amdgcn_mfma_f32_16x16x32_bf16(af[m], bfr[n], acc[m][n], 0, 0, 0);
    __syncthreads();   // protect LDS before next stage
  }

  // C/D layout: col = lane&15, row = (lane>>4)*4 + reg
  const int crow = (int)bm + wm + (lane >> 4) * 4;
  const int ccol = (int)bn + wn + (lane & 15);
  if constexpr (OUT_BF) {
    u16* C = (u16*)Cv;
#pragma unroll
    for (int m = 0; m < 4; ++m)
#pragma unroll
      for (int n = 0; n < 4; ++n)
#pragma unroll
        for (int r = 0; r < 4; ++r)
          C[(size_t)(crow + m * 16 + r) * N + ccol + n * 16] = f2bf(acc[m][n][r]);
  } else {
    float* C = (float*)Cv;
#pragma unroll
    for (int m = 0; m < 4; ++m)
#pragma unroll
      for (int n = 0; n < 4; ++n)
#pragma unroll
        for (int r = 0; r < 4; ++r)
          C[(size_t)(crow + m * 16 + r) * N + ccol + n * 16] = acc[m][n][r];
  }
}

// ================= fp32 -> bf16 straight convert (8 elems/thread) ============
__global__ __launch_bounds__(256) void convert_f2b(const float* __restrict__ X,
                                                   u16* __restrict__ Y, int n8) {
  int i = blockIdx.x * 256 + threadIdx.x;
  if (i >= n8) return;
  const float4* xp = (const float4*)X;
  float4 a = xp[i * 2], b = xp[i * 2 + 1];
  u16x8 o;
  o[0] = f2bf(a.x); o[1] = f2bf(a.y); o[2] = f2bf(a.z); o[3] = f2bf(a.w);
  o[4] = f2bf(b.x); o[5] = f2bf(b.y); o[6] = f2bf(b.z); o[7] = f2bf(b.w);
  ((u16x8*)Y)[i] = o;
}

// ================= fp32 [R,C] -> bf16 transpose [C,R] ========================
__global__ __launch_bounds__(256) void transpose_f2b(const float* __restrict__ X,
                                                     u16* __restrict__ Y, int R, int C) {
  __shared__ float tile[32][33];
  const int bx = blockIdx.x * 32;  // col base
  const int by = blockIdx.y * 32;  // row base
  const int tx = threadIdx.x & 31;
  const int ty = threadIdx.x >> 5; // 0..7
#pragma unroll
  for (int i = 0; i < 32; i += 8)
    tile[ty + i][tx] = X[(size_t)(by + ty + i) * C + bx + tx];
  __syncthreads();
#pragma unroll
  for (int i = 0; i < 32; i += 8)
    Y[(size_t)(bx + ty + i) * R + by + tx] = f2bf(tile[tx][ty + i]);
}

// ================= row L2-normalize fp32 -> bf16, D = 512 ====================
__global__ __launch_bounds__(128) void rownorm_bf(const float* __restrict__ x,
                                                  u16* __restrict__ y) {
  const int row = blockIdx.x;
  const float* r = x + (size_t)row * ATT_HC;
  const int t = threadIdx.x;
  float4 v = ((const float4*)r)[t];
  float s = v.x * v.x + v.y * v.y + v.z * v.z + v.w * v.w;
#pragma unroll
  for (int off = 32; off > 0; off >>= 1) s += __shfl_xor(s, off);
  __shared__ float red[2];
  if ((t & 63) == 0) red[t >> 6] = s;
  __syncthreads();
  float inv = 1.0f / fmaxf(sqrtf(red[0] + red[1]), 1e-8f);
  u16x4 o;
  o[0] = f2bf(v.x * inv); o[1] = f2bf(v.y * inv);
  o[2] = f2bf(v.z * inv); o[3] = f2bf(v.w * inv);
  ((u16x4*)(y + (size_t)row * ATT_HC))[t] = o;
}

// ========== masked softmax rows of S[2048,2048] fp32 -> bf16 P ==============
// raw = where(S > thresh, S, -9e15); P = softmax(raw * T); masked-out -> 0
__global__ __launch_bounds__(256) void masked_softmax_bf(const float* __restrict__ S,
                                                         u16* __restrict__ P) {
  const int row = blockIdx.x;
  const float* r = S + (size_t)row * N_CLS;
  const int t = threadIdx.x;
  const float4* rf = (const float4*)r;
  float4 v0 = rf[t];
  float4 v1 = rf[t + 256];
  float vals[8] = {v0.x, v0.y, v0.z, v0.w, v1.x, v1.y, v1.z, v1.w};
  __shared__ float red[4];

  float m = -1e30f;
#pragma unroll
  for (int i = 0; i < 8; ++i)
    if (vals[i] > THRESH) m = fmaxf(m, vals[i]);
#pragma unroll
  for (int off = 32; off > 0; off >>= 1) m = fmaxf(m, __shfl_xor(m, off));
  if ((t & 63) == 0) red[t >> 6] = m;
  __syncthreads();
  m = fmaxf(fmaxf(red[0], red[1]), fmaxf(red[2], red[3]));
  __syncthreads();

  float e[8], s = 0.0f;
#pragma unroll
  for (int i = 0; i < 8; ++i) {
    e[i] = (vals[i] > THRESH) ? __expf((vals[i] - m) * TEMP) : 0.0f;
    s += e[i];
  }
#pragma unroll
  for (int off = 32; off > 0; off >>= 1) s += __shfl_xor(s, off);
  if ((t & 63) == 0) red[t >> 6] = s;
  __syncthreads();
  s = red[0] + red[1] + red[2] + red[3];
  float inv = 1.0f / s;

  u16* pr = P + (size_t)row * N_CLS;
  u16x4 o0, o1;
  o0[0] = f2bf(e[0] * inv); o0[1] = f2bf(e[1] * inv);
  o0[2] = f2bf(e[2] * inv); o0[3] = f2bf(e[3] * inv);
  o1[0] = f2bf(e[4] * inv); o1[1] = f2bf(e[5] * inv);
  o1[2] = f2bf(e[6] * inv); o1[3] = f2bf(e[7] * inv);
  ((u16x4*)pr)[t] = o0;
  ((u16x4*)(pr + 1024))[t] = o1;
}

// ================= segment mean machinery ====================================
__global__ void zero_ints_kernel(int* __restrict__ p, int n) {
  int i = blockIdx.x * 256 + threadIdx.x;
  if (i < n) p[i] = 0;
}
__global__ void count_kernel(const int* __restrict__ labels, int* __restrict__ counts, int n) {
  int i = blockIdx.x * 256 + threadIdx.x;
  if (i < n) atomicAdd(&counts[labels[i]], 1);
}
__global__ void scan_kernel(const int* __restrict__ counts, int* __restrict__ offs, int n) {
  if (threadIdx.x == 0 && blockIdx.x == 0) {
    int s = 0;
    for (int i = 0; i < n; ++i) { offs[i] = s; s += counts[i]; }
  }
}
__global__ void scatter_kernel(const int* __restrict__ labels, const int* __restrict__ offs,
                               int* __restrict__ cursor, int* __restrict__ list, int n) {
  int i = blockIdx.x * 256 + threadIdx.x;
  if (i < n) {
    int l = labels[i];
    int pos = atomicAdd(&cursor[l], 1);
    list[offs[l] + pos] = i;
  }
}
__global__ __launch_bounds__(512) void pool_kernel(const float* __restrict__ img,
                                                   const int* __restrict__ list,
                                                   const int* __restrict__ offs,
                                                   const int* __restrict__ counts,
                                                   const int* __restrict__ target,
                                                   float* __restrict__ protos) {
  const int j = blockIdx.x;
  const int c = target[j];
  const int beg = offs[c];
  const int cnt = counts[c];
  const int t = threadIdx.x; // 512 threads * float4 = 2048 dims
  float4 acc = {0.f, 0.f, 0.f, 0.f};
  for (int q = 0; q < cnt; ++q) {
    int idx = list[beg + q];
    float4 v = ((const float4*)(img + (size_t)idx * IMAGE_DIM))[t];
    acc.x += v.x; acc.y += v.y; acc.z += v.z; acc.w += v.w;
  }
  float invc = 1.0f / (float)cnt;
  acc.x *= invc; acc.y *= invc; acc.z *= invc; acc.w *= invc;
  ((float4*)(protos + (size_t)j * IMAGE_DIM))[t] = acc;
}

// ================= launch ====================================================
extern "C" void kernel_launch(void* const* d_in, const int* in_sizes, int n_in,
                              void* d_out, int out_size, void* d_ws, size_t ws_size,
                              hipStream_t stream) {
  const float* image_feats = (const float*)d_in[0];   // [65536, 2048]
  const float* attributes = (const float*)d_in[1];    // [2048, 1024]
  const int* labels = (const int*)d_in[2];            // [65536]
  const int* target = (const int*)d_in[3];            // [2048]
  const float* att_g_a = (const float*)d_in[4];       // [1024, 512]
  const float* att_g_v = (const float*)d_in[5];       // [1024, 512]
  float* out = (float*)d_out;                         // [2048, 2048]

  char* w = (char*)d_ws;
  u16* attr_bf = (u16*)(w + 0);                 // [2048,1024] 4 MiB (later reused as ao_bf)
  u16* attrT_bf = (u16*)(w + (4u << 20));       // [1024,2048] 4 MiB
  u16* gaT_bf = (u16*)(w + (8u << 20));         // [512,1024]  1 MiB
  u16* gvT_bf = (u16*)(w + (9u << 20));         // [512,1024]  1 MiB
  float* a_f32 = (float*)(w + (10u << 20));     // [2048,512]  4 MiB (a1 then a2)
  u16* an_bf = (u16*)(w + (14u << 20));         // [2048,512]  2 MiB
  float* S_f32 = (float*)(w + (16u << 20));     // [2048,2048] 16 MiB (later protos_f32)
  u16* P_bf = (u16*)(w + (32u << 20));          // [2048,2048] 8 MiB (attn1 then attn2)
  u16* protosT_bf = (u16*)(w + (40u << 20));    // [2048,2048] 8 MiB
  int* counts = (int*)(w + (48u << 20));
  int* cursor = counts + N_CLS;
  int* offs = cursor + N_CLS;
  int* list = offs + N_CLS;                     // [65536]
  u16* ao_bf = attr_bf;                         // alias: attr_bf dead after GEMM1
  float* protos_f32 = S_f32;                    // alias: S dead after softmax2

  // ---- operand converts / transposes ----
  convert_f2b<<<(N_CLS * ATT_DIM / 8 + 255) / 256, 256, 0, stream>>>(
      attributes, attr_bf, N_CLS * ATT_DIM / 8);
  transpose_f2b<<<dim3(ATT_DIM / 32, N_CLS / 32), 256, 0, stream>>>(
      attributes, attrT_bf, N_CLS, ATT_DIM);
  transpose_f2b<<<dim3(ATT_HC / 32, ATT_DIM / 32), 256, 0, stream>>>(
      att_g_a, gaT_bf, ATT_DIM, ATT_HC);
  transpose_f2b<<<dim3(ATT_HC / 32, ATT_DIM / 32), 256, 0, stream>>>(
      att_g_v, gvT_bf, ATT_DIM, ATT_HC);

  // ---- segment-mean index build ----
  zero_ints_kernel<<<(2 * N_CLS + 255) / 256, 256, 0, stream>>>(counts, 2 * N_CLS);
  count_kernel<<<(N_IMG + 255) / 256, 256, 0, stream>>>(labels, counts, N_IMG);
  scan_kernel<<<1, 64, 0, stream>>>(counts, offs, N_CLS);
  scatter_kernel<<<(N_IMG + 255) / 256, 256, 0, stream>>>(labels, offs, cursor, list, N_IMG);

  // ---- a1 = attributes @ att_g_a ; normalize -> bf16 ----
  gemm_nt_bf16<false><<<dim3(ATT_HC / 128, N_CLS / 128), 256, 0, stream>>>(
      attr_bf, gaT_bf, a_f32, N_CLS, ATT_HC, ATT_DIM);
  rownorm_bf<<<N_CLS, 128, 0, stream>>>(a_f32, an_bf);

  // ---- attn1 = softmax(mask(a1n @ a1n^T)) -> bf16 ----
  gemm_nt_bf16<false><<<dim3(N_CLS / 128, N_CLS / 128), 256, 0, stream>>>(
      an_bf, an_bf, S_f32, N_CLS, N_CLS, ATT_HC);
  masked_softmax_bf<<<N_CLS, 256, 0, stream>>>(S_f32, P_bf);

  // ---- att_outs = attn1 @ attributes (bf16 out) ----
  gemm_nt_bf16<true><<<dim3(ATT_DIM / 128, N_CLS / 128), 256, 0, stream>>>(
      P_bf, attrT_bf, ao_bf, N_CLS, ATT_DIM, N_CLS);

  // ---- a2 = att_outs @ att_g_v ; normalize -> bf16 ----
  gemm_nt_bf16<false><<<dim3(ATT_HC / 128, N_CLS / 128), 256, 0, stream>>>(
      ao_bf, gvT_bf, a_f32, N_CLS, ATT_HC, ATT_DIM);
  rownorm_bf<<<N_CLS, 128, 0, stream>>>(a_f32, an_bf);

  // ---- attention = softmax(mask(a2n @ a2n^T)) -> bf16 ----
  gemm_nt_bf16<false><<<dim3(N_CLS / 128, N_CLS / 128), 256, 0, stream>>>(
      an_bf, an_bf, S_f32, N_CLS, N_CLS, ATT_HC);
  masked_softmax_bf<<<N_CLS, 256, 0, stream>>>(S_f32, P_bf);

  // ---- protos (segment mean, reordered) ; transpose -> bf16 ----
  pool_kernel<<<N_CLS, 512, 0, stream>>>(image_feats, list, offs, counts, target, protos_f32);
  transpose_f2b<<<dim3(IMAGE_DIM / 32, N_CLS / 32), 256, 0, stream>>>(
      protos_f32, protosT_bf, N_CLS, IMAGE_DIM);

  // ---- out = attention @ protos ----
  gemm_nt_bf16<false><<<dim3(IMAGE_DIM / 128, N_CLS / 128), 256, 0, stream>>>(
      P_bf, protosT_bf, out, N_CLS, IMAGE_DIM, N_CLS);
}